// Round 8
// baseline (943.242 us; speedup 1.0000x reference)
//
#include <hip/hip_runtime.h>
#include <hip/hip_bf16.h>

// LinkPredictorGAT: out[e] = relu(concat(z[src[e]], z[dst[e]]) @ W1 + b1) @ W2 + b2
// R7 = R6 structure (full B^T in LDS, XOR swizzle -> 0 bank conflicts, persistent
// 512-thr blocks, zero steady-state barriers) with HALF the accumulator tile:
// mf=2, nf=8 (32 edges x 128 cols per wave), acc 128->64 AGPRs.
// R4/R6 post-mortem: mf=4 tile needs ~120+ arch VGPRs -> allocator spills one
// short8 per k-step (WRITE_SIZE 258 MB = 256blk*512thr*15.3tiles*16ks*16B).
// mf=2 leaves ~30 arch regs slack -> no spill by construction.

typedef __attribute__((ext_vector_type(4))) float floatx4;
typedef __attribute__((ext_vector_type(8))) short short8;

__device__ __forceinline__ unsigned short bf16rne(float x) {
    unsigned int u = __float_as_uint(x);
    u += 0x7fffu + ((u >> 16) & 1u);
    return (unsigned short)(u >> 16);
}

// ---- convert z (fp32 -> bf16), float4 per thread ----
__global__ void cvt_z(const float* __restrict__ z, unsigned short* __restrict__ zb, int n4) {
    int i = blockIdx.x * blockDim.x + threadIdx.x;
    if (i < n4) {
        float4 f = ((const float4*)z)[i];
        ushort4 u;
        u.x = bf16rne(f.x); u.y = bf16rne(f.y);
        u.z = bf16rne(f.z); u.w = bf16rne(f.w);
        ((ushort4*)zb)[i] = u;
    }
}

// ---- convert W1 [512][128] fp32 -> BTc, the EXACT (swizzled) LDS image of B^T ----
// Layout (shorts): L(s,n,g',j) = s*4096 + n*32 + g'*8 + j, with s=k>>5, g=(k>>3)&3,
// j=k&7, g' = g ^ ((n>>1)&3). Verified R6: reader pattern -> SQ_LDS_BANK_CONFLICT = 0.
__global__ void cvt_w1(const float* __restrict__ W1, unsigned short* __restrict__ BTc) {
    int t = blockIdx.x * blockDim.x + threadIdx.x;   // 0..65535
    int s = t >> 12, rem = t & 4095;
    int n = rem >> 5, rem2 = rem & 31;
    int gp = rem2 >> 3, j = rem2 & 7;
    int g = gp ^ ((n >> 1) & 3);
    int k = s * 32 + g * 8 + j;
    BTc[t] = bf16rne(W1[k * 128 + n]);
}

// ---- fused gather + GEMM(512x128) + bias + relu + GEMV(W2) ----
// 512 threads = 8 waves, persistent (grid <= 256; 128 KB LDS -> 1 block/CU).
// Wave tile 32 edges x 128 cols (mf=2, nf=8); tile = 256 edges/block-iteration.
template <bool ABF16>
__global__ __launch_bounds__(512, 2)   // 2 waves/EU -> 256 unified regs/wave
void fused_mlp(const float* __restrict__ zf, const unsigned short* __restrict__ zb,
               const int* __restrict__ eli, int E, int nnodes,
               const unsigned short* __restrict__ BTc,
               const float* __restrict__ b1, const float* __restrict__ W2,
               const float* __restrict__ b2, float* __restrict__ out, int ntiles)
{
    __shared__ unsigned short btile[16 * 128 * 32];   // 128 KB swizzled B image

    const int t = threadIdx.x;
    const int wid = t >> 6;
    const int lane = t & 63;
    const int l15 = lane & 15;
    const int quad = lane >> 4;

    // ---- one-time stage: flat 128 KB coalesced copy; the ONLY barrier ----
#pragma unroll
    for (int i = 0; i < 16; ++i) {
        int p = i * 512 + t;
        *(short8*)&btile[p * 8] = *(const short8*)(BTc + p * 8);
    }
    __syncthreads();

    const char* zbb = (const char*)(ABF16 ? (const void*)zb : (const void*)zf);
    const int swz = (l15 >> 1) & 3;
    const unsigned short* bbase = btile + l15 * 32 + (quad ^ swz) * 8;

    // epilogue constants, loaded once (persistent kernel; reg slack is ample)
    float b1v[8], w2v[8];
#pragma unroll
    for (int nf = 0; nf < 8; ++nf) {
        int c = nf * 16 + l15;
        b1v[nf] = b1[c];
        w2v[nf] = W2[c];
    }
    const float b2s = b2[0];

    auto loadIdx = [&](int tile, unsigned* os, unsigned* od) {
        const int m0 = tile * 256 + wid * 32;
#pragma unroll
        for (int mf = 0; mf < 2; ++mf) {
            int e = m0 + mf * 16 + l15;
            e = e < E ? e : E - 1;                     // clamp tail (stores masked)
            int s = eli[e];
            int d = eli[E + e];
            s = s < 0 ? 0 : (s >= nnodes ? nnodes - 1 : s);
            d = d < 0 ? 0 : (d >= nnodes ? nnodes - 1 : d);
            os[mf] = (unsigned)s * 512u;               // bf16 row = 512 B
            od[mf] = (unsigned)d * 512u;
        }
    };

    auto load_a = [&](const unsigned* os, const unsigned* od, int ks, short8* dst) {
        const unsigned* off = (ks < 8) ? os : od;
        if constexpr (ABF16) {
            const int cb = (ks & 7) * 64 + quad * 16;
#pragma unroll
            for (int mf = 0; mf < 2; ++mf)
                dst[mf] = *(const short8*)(zbb + (size_t)off[mf] + cb);
        } else {
            const int cb = (ks & 7) * 128 + quad * 32;
#pragma unroll
            for (int mf = 0; mf < 2; ++mf) {
                const float* pf = (const float*)(zbb + (size_t)off[mf] * 2 + cb);
                float4 f0 = *(const float4*)pf;
                float4 f1 = *(const float4*)(pf + 4);
                short8 av;
                av[0] = (short)bf16rne(f0.x); av[1] = (short)bf16rne(f0.y);
                av[2] = (short)bf16rne(f0.z); av[3] = (short)bf16rne(f0.w);
                av[4] = (short)bf16rne(f1.x); av[5] = (short)bf16rne(f1.y);
                av[6] = (short)bf16rne(f1.z); av[7] = (short)bf16rne(f1.w);
                dst[mf] = av;
            }
        }
    };

    unsigned offs[2], offd[2], offs_n[2], offd_n[2];
    short8 A[3][2];                                    // depth-2 rolling A prefetch

    int tile = blockIdx.x;
    if (tile < ntiles) {
        loadIdx(tile, offs, offd);
        load_a(offs, offd, 0, A[0]);
    }

    for (; tile < ntiles; tile += gridDim.x) {
        const int m0 = tile * 256 + wid * 32;
        const int tnext = tile + gridDim.x;

        load_a(offs, offd, 1, A[1]);

        floatx4 acc[2][8];
#pragma unroll
        for (int mf = 0; mf < 2; ++mf)
#pragma unroll
            for (int nf = 0; nf < 8; ++nf)
                acc[mf][nf] = (floatx4){0.f, 0.f, 0.f, 0.f};

#pragma unroll
        for (int ks = 0; ks < 16; ++ks) {
            if (ks < 14) load_a(offs, offd, ks + 2, A[(ks + 2) % 3]);

            const unsigned short* bs = bbase + ks * 4096;
            short8 bfr[8];
#pragma unroll
            for (int nf = 0; nf < 8; ++nf)
                bfr[nf] = *(const short8*)(bs + nf * 512);   // conflict-free (R6: 0)

            const short8* ac = A[ks % 3];
#pragma unroll
            for (int nf = 0; nf < 8; ++nf)
#pragma unroll
                for (int mf = 0; mf < 2; ++mf)
                    acc[mf][nf] = __builtin_amdgcn_mfma_f32_16x16x32_bf16(
                        ac[mf], bfr[nf], acc[mf][nf], 0, 0, 0);
        }

        // prefetch next tile's indices; epilogue shuffle chain covers the latency
        if (tnext < ntiles) loadIdx(tnext, offs_n, offd_n);

        // epilogue: C/D layout col = lane&15 (+16*nf), row = quad*4 + r (+16*mf)
#pragma unroll
        for (int mf = 0; mf < 2; ++mf) {
#pragma unroll
            for (int r = 0; r < 4; ++r) {
                float s = 0.f;
#pragma unroll
                for (int nf = 0; nf < 8; ++nf) {
                    float v = acc[mf][nf][r] + b1v[nf];
                    v = v > 0.f ? v : 0.f;
                    s = fmaf(v, w2v[nf], s);
                }
                s += __shfl_xor(s, 1);
                s += __shfl_xor(s, 2);
                s += __shfl_xor(s, 4);
                s += __shfl_xor(s, 8);
                if (l15 == 0) {
                    int e = m0 + mf * 16 + quad * 4 + r;
                    if (e < E) out[e] = s + b2s;
                }
            }
        }

        if (tnext < ntiles) {
#pragma unroll
            for (int i = 0; i < 2; ++i) { offs[i] = offs_n[i]; offd[i] = offd_n[i]; }
            load_a(offs, offd, 0, A[0]);               // next tile's ks=0 in flight
        }
    }
}

// ---- emergency fallback (tiny ws): one block per edge, fp32 vector ----
__global__ void naive_edge(const float* __restrict__ z, const int* __restrict__ eli,
                           int E, int nnodes,
                           const float* __restrict__ W1, const float* __restrict__ b1,
                           const float* __restrict__ W2, const float* __restrict__ b2,
                           float* __restrict__ out)
{
    __shared__ float red[2];
    int e = blockIdx.x;
    int j = threadIdx.x;
    int s = eli[e], d = eli[E + e];
    s = s < 0 ? 0 : (s >= nnodes ? nnodes - 1 : s);
    d = d < 0 ? 0 : (d >= nnodes ? nnodes - 1 : d);
    const float* zs = z + (long long)s * 256;
    const float* zd = z + (long long)d * 256;
    float h = b1[j];
    for (int i = 0; i < 256; ++i) h = fmaf(zs[i], W1[i * 128 + j], h);
    for (int i = 0; i < 256; ++i) h = fmaf(zd[i], W1[(256 + i) * 128 + j], h);
    h = h > 0.f ? h : 0.f;
    float v = h * W2[j];
    v += __shfl_xor(v, 1);  v += __shfl_xor(v, 2);  v += __shfl_xor(v, 4);
    v += __shfl_xor(v, 8);  v += __shfl_xor(v, 16); v += __shfl_xor(v, 32);
    if ((threadIdx.x & 63) == 0) red[threadIdx.x >> 6] = v;
    __syncthreads();
    if (threadIdx.x == 0) out[e] = red[0] + red[1] + b2[0];
}

extern "C" void kernel_launch(void* const* d_in, const int* in_sizes, int n_in,
                              void* d_out, int out_size, void* d_ws, size_t ws_size,
                              hipStream_t stream) {
    const float* z   = (const float*)d_in[0];
    const int*   eli = (const int*)d_in[1];      // int64 in reference -> int32 on device
    const float* W1  = (const float*)d_in[2];
    const float* b1  = (const float*)d_in[3];
    const float* W2  = (const float*)d_in[4];
    const float* b2  = (const float*)d_in[5];
    float*       out = (float*)d_out;

    const int E      = in_sizes[1] / 2;
    const int nnodes = in_sizes[0] / 256;

    const size_t ZB  = (size_t)nnodes * 256 * 2;   // z in bf16
    const size_t BTB = (size_t)512 * 128 * 2;      // B^T (swizzled image) in bf16

    const int ntiles = (E + 255) / 256;
    const int grid_main = ntiles < 256 ? ntiles : 256;   // persistent, 1 block/CU

    if (ws_size >= ZB + BTB) {
        unsigned short* zb  = (unsigned short*)d_ws;
        unsigned short* BTc = (unsigned short*)((char*)d_ws + ZB);
        int n4 = nnodes * 64;
        cvt_z<<<(n4 + 255) / 256, 256, 0, stream>>>(z, zb, n4);
        cvt_w1<<<256, 256, 0, stream>>>(W1, BTc);
        fused_mlp<true><<<grid_main, 512, 0, stream>>>(nullptr, zb, eli, E, nnodes, BTc, b1, W2, b2, out, ntiles);
    } else if (ws_size >= BTB) {
        unsigned short* BTc = (unsigned short*)d_ws;
        cvt_w1<<<256, 256, 0, stream>>>(W1, BTc);
        fused_mlp<false><<<grid_main, 512, 0, stream>>>(z, nullptr, eli, E, nnodes, BTc, b1, W2, b2, out, ntiles);
    } else {
        naive_edge<<<E, 128, 0, stream>>>(z, eli, E, nnodes, W1, b1, W2, b2, out);
    }
}

// Round 9
// 338.039 us; speedup vs baseline: 2.7903x; 2.7903x over previous
//
#include <hip/hip_runtime.h>
#include <hip/hip_bf16.h>

// LinkPredictorGAT: out[e] = relu(concat(z[src[e]], z[dst[e]]) @ W1 + b1) @ W2 + b2
// R8 = R5 skeleton (256-thr blocks, 3907 blocks, double-buffered LDS B — the only
// lineage that performs: 217us) + three deltas:
//   1. XOR-swizzled B image (R6/R7-verified: SQ_LDS_BANK_CONFLICT = 0)
//   2. BK=128 chunks -> 4 barriers instead of 8 (R2->R5 A/B: ~5.6us/barrier)
//   3. global_load_lds width=16 staging: zero staging VGPRs/VALU (m97 lever);
//      BTc is a LINEAR image of the swizzled LDS layout so the wave-uniform-base
//      + lane*16 constraint is satisfied exactly.
// Abandoned: 512-thr persistent full-B-LDS (R4/R6/R7 all ~620-750us, structural).

typedef __attribute__((ext_vector_type(4))) float floatx4;
typedef __attribute__((ext_vector_type(8))) short short8;

__device__ __forceinline__ unsigned short bf16rne(float x) {
    unsigned int u = __float_as_uint(x);
    u += 0x7fffu + ((u >> 16) & 1u);
    return (unsigned short)(u >> 16);
}

// async global->LDS, 16 B per lane; LDS dest = wave-uniform base + lane*16.
// Address-space pointers formed via integer round-trip (generic LDS ptr keeps the
// LDS offset in its low 32 bits on AMDGPU).
__device__ __forceinline__ void gl_lds16(const void* g, void* l) {
    __builtin_amdgcn_global_load_lds(
        (const __attribute__((address_space(1))) void*)(unsigned long long)g,
        (__attribute__((address_space(3))) void*)(unsigned)(unsigned long long)l,
        16, 0, 0);
}

// ---- convert z (fp32 -> bf16), float4 per thread ----
__global__ void cvt_z(const float* __restrict__ z, unsigned short* __restrict__ zb, int n4) {
    int i = blockIdx.x * blockDim.x + threadIdx.x;
    if (i < n4) {
        float4 f = ((const float4*)z)[i];
        ushort4 u;
        u.x = bf16rne(f.x); u.y = bf16rne(f.y);
        u.z = bf16rne(f.z); u.w = bf16rne(f.w);
        ((ushort4*)zb)[i] = u;
    }
}

// ---- convert W1 [512][128] fp32 -> BTc, linear image of the swizzled B layout ----
// L(s,n,g',j) = s*4096 + n*32 + g'*8 + j (shorts); s=k>>5, g=(k>>3)&3, j=k&7,
// g' = g ^ ((n>>1)&3). Reader: 0 bank conflicts (verified R6/R7).
__global__ void cvt_w1(const float* __restrict__ W1, unsigned short* __restrict__ BTc) {
    int t = blockIdx.x * blockDim.x + threadIdx.x;   // 0..65535
    int s = t >> 12, rem = t & 4095;
    int n = rem >> 5, rem2 = rem & 31;
    int gp = rem2 >> 3, j = rem2 & 7;
    int g = gp ^ ((n >> 1) & 3);
    int k = s * 32 + g * 8 + j;
    BTc[t] = bf16rne(W1[k * 128 + n]);
}

// ---- fused gather + GEMM(512x128) + bias + relu + GEMV(W2) ----
// 256 threads = 4 waves; wave tile 64 edges x 128 cols (mf=4, nf=8); 256 edges/block.
// LDS: 2 x 32 KB chunk buffers (BK=128 = 4 K32 slabs each) = 64 KB -> 2 blocks/CU.
template <bool ABF16>
__global__ __launch_bounds__(256, 2)
void fused_mlp(const float* __restrict__ zf, const unsigned short* __restrict__ zb,
               const int* __restrict__ eli, int E, int nnodes,
               const unsigned short* __restrict__ BTc,
               const float* __restrict__ b1, const float* __restrict__ W2,
               const float* __restrict__ b2, float* __restrict__ out)
{
    __shared__ unsigned short btile[2][4][128][32];   // [buf][slab][n][32] = 64 KB

    const int t = threadIdx.x;
    const int wid = t >> 6;
    const int lane = t & 63;
    const int l15 = lane & 15;
    const int quad = lane >> 4;
    const int m0 = blockIdx.x * 256 + wid * 64;

    // gather byte offsets for this lane's 4 src / 4 dst rows
    unsigned offs[4], offd[4];
#pragma unroll
    for (int mf = 0; mf < 4; ++mf) {
        int e = m0 + mf * 16 + l15;
        e = e < E ? e : E - 1;                 // clamp tail (stores masked later)
        int s = eli[e];
        int d = eli[E + e];
        s = s < 0 ? 0 : (s >= nnodes ? nnodes - 1 : s);
        d = d < 0 ? 0 : (d >= nnodes ? nnodes - 1 : d);
        offs[mf] = (unsigned)s * 512u;         // bf16 row = 512 B (fp32 path scales x2)
        offd[mf] = (unsigned)d * 512u;
    }
    const char* zbb = (const char*)(ABF16 ? (const void*)zb : (const void*)zf);

    const int swz = (l15 >> 1) & 3;
    const unsigned short* bbase = &btile[0][0][0][0] + l15 * 32 + (quad ^ swz) * 8;

    // ---- async stage of one 32 KB chunk (kc in [0,4)) into buf; zero VGPR cost ----
    auto stage = [&](int kc, int buf) {
        const char* g = (const char*)BTc + kc * 32768 + wid * 1024 + lane * 16;
        char* l = (char*)&btile[buf][0][0][0] + wid * 1024 + lane * 16;
#pragma unroll
        for (int i = 0; i < 8; ++i)
            gl_lds16(g + i * 4096, l + i * 4096);
    };

    // ---- A loader: ks in [0,16); src half (ks<8) or dst half ----
    auto load_a = [&](int ks, short8* dst) {
        const unsigned* off = (ks < 8) ? offs : offd;
        if constexpr (ABF16) {
            const int cb = (ks & 7) * 64 + quad * 16;
#pragma unroll
            for (int mf = 0; mf < 4; ++mf)
                dst[mf] = *(const short8*)(zbb + (size_t)off[mf] + cb);
        } else {
            const int cb = (ks & 7) * 128 + quad * 32;
#pragma unroll
            for (int mf = 0; mf < 4; ++mf) {
                const float* pf = (const float*)(zbb + (size_t)off[mf] * 2 + cb);
                float4 f0 = *(const float4*)pf;
                float4 f1 = *(const float4*)(pf + 4);
                short8 av;
                av[0] = (short)bf16rne(f0.x); av[1] = (short)bf16rne(f0.y);
                av[2] = (short)bf16rne(f0.z); av[3] = (short)bf16rne(f0.w);
                av[4] = (short)bf16rne(f1.x); av[5] = (short)bf16rne(f1.y);
                av[6] = (short)bf16rne(f1.z); av[7] = (short)bf16rne(f1.w);
                dst[mf] = av;
            }
        }
    };

    floatx4 acc[4][8];
#pragma unroll
    for (int mf = 0; mf < 4; ++mf)
#pragma unroll
        for (int nf = 0; nf < 8; ++nf)
            acc[mf][nf] = (floatx4){0.f, 0.f, 0.f, 0.f};

    short8 A[3][4];                            // depth-2 rolling A prefetch
    stage(0, 0);
    load_a(0, A[0]);
    load_a(1, A[1]);
    __syncthreads();                           // chunk0 in LDS; A0/A1 drained-complete

#pragma unroll
    for (int kc = 0; kc < 4; ++kc) {           // 4 chunks of BK=128; 3 more barriers
        if (kc < 3) stage(kc + 1, (kc + 1) & 1);

#pragma unroll
        for (int s4 = 0; s4 < 4; ++s4) {
            const int ks = kc * 4 + s4;
            if (ks + 2 < 16) load_a(ks + 2, A[(ks + 2) % 3]);

            const unsigned short* bs = bbase + (kc & 1) * 16384 + s4 * 4096;
            short8 bfr[8];
#pragma unroll
            for (int nf = 0; nf < 8; ++nf)
                bfr[nf] = *(const short8*)(bs + nf * 512);   // swizzled: 0 conflicts

            const short8* ac = A[ks % 3];
#pragma unroll
            for (int nf = 0; nf < 8; ++nf)
#pragma unroll
                for (int mf = 0; mf < 4; ++mf)
                    acc[mf][nf] = __builtin_amdgcn_mfma_f32_16x16x32_bf16(
                        ac[mf], bfr[nf], acc[mf][nf], 0, 0, 0);
        }

        if (kc < 3) __syncthreads();           // drains staging vmcnt; publishes buf
    }

    // ---- epilogue (consts loaded late; C/D: col=lane&15+16nf, row=quad*4+r+16mf) ----
    const float b2s = b2[0];
    float b1v[8], w2v[8];
#pragma unroll
    for (int nf = 0; nf < 8; ++nf) {
        int c = nf * 16 + l15;
        b1v[nf] = b1[c];
        w2v[nf] = W2[c];
    }
#pragma unroll
    for (int mf = 0; mf < 4; ++mf) {
#pragma unroll
        for (int r = 0; r < 4; ++r) {
            float s = 0.f;
#pragma unroll
            for (int nf = 0; nf < 8; ++nf) {
                float v = acc[mf][nf][r] + b1v[nf];
                v = v > 0.f ? v : 0.f;
                s = fmaf(v, w2v[nf], s);
            }
            s += __shfl_xor(s, 1);
            s += __shfl_xor(s, 2);
            s += __shfl_xor(s, 4);
            s += __shfl_xor(s, 8);
            if (l15 == 0) {
                int e = m0 + mf * 16 + quad * 4 + r;
                if (e < E) out[e] = s + b2s;
            }
        }
    }
}

// ---- emergency fallback (tiny ws): one block per edge, fp32 vector ----
__global__ void naive_edge(const float* __restrict__ z, const int* __restrict__ eli,
                           int E, int nnodes,
                           const float* __restrict__ W1, const float* __restrict__ b1,
                           const float* __restrict__ W2, const float* __restrict__ b2,
                           float* __restrict__ out)
{
    __shared__ float red[2];
    int e = blockIdx.x;
    int j = threadIdx.x;
    int s = eli[e], d = eli[E + e];
    s = s < 0 ? 0 : (s >= nnodes ? nnodes - 1 : s);
    d = d < 0 ? 0 : (d >= nnodes ? nnodes - 1 : d);
    const float* zs = z + (long long)s * 256;
    const float* zd = z + (long long)d * 256;
    float h = b1[j];
    for (int i = 0; i < 256; ++i) h = fmaf(zs[i], W1[i * 128 + j], h);
    for (int i = 0; i < 256; ++i) h = fmaf(zd[i], W1[(256 + i) * 128 + j], h);
    h = h > 0.f ? h : 0.f;
    float v = h * W2[j];
    v += __shfl_xor(v, 1);  v += __shfl_xor(v, 2);  v += __shfl_xor(v, 4);
    v += __shfl_xor(v, 8);  v += __shfl_xor(v, 16); v += __shfl_xor(v, 32);
    if ((threadIdx.x & 63) == 0) red[threadIdx.x >> 6] = v;
    __syncthreads();
    if (threadIdx.x == 0) out[e] = red[0] + red[1] + b2[0];
}

extern "C" void kernel_launch(void* const* d_in, const int* in_sizes, int n_in,
                              void* d_out, int out_size, void* d_ws, size_t ws_size,
                              hipStream_t stream) {
    const float* z   = (const float*)d_in[0];
    const int*   eli = (const int*)d_in[1];      // int64 in reference -> int32 on device
    const float* W1  = (const float*)d_in[2];
    const float* b1  = (const float*)d_in[3];
    const float* W2  = (const float*)d_in[4];
    const float* b2  = (const float*)d_in[5];
    float*       out = (float*)d_out;

    const int E      = in_sizes[1] / 2;
    const int nnodes = in_sizes[0] / 256;

    const size_t ZB  = (size_t)nnodes * 256 * 2;   // z in bf16
    const size_t BTB = (size_t)512 * 128 * 2;      // B^T (swizzled linear image)

    const int grid_main = (E + 255) / 256;

    if (ws_size >= ZB + BTB) {
        unsigned short* zb  = (unsigned short*)d_ws;
        unsigned short* BTc = (unsigned short*)((char*)d_ws + ZB);
        int n4 = nnodes * 64;
        cvt_z<<<(n4 + 255) / 256, 256, 0, stream>>>(z, zb, n4);
        cvt_w1<<<256, 256, 0, stream>>>(W1, BTc);
        fused_mlp<true><<<grid_main, 256, 0, stream>>>(nullptr, zb, eli, E, nnodes, BTc, b1, W2, b2, out);
    } else if (ws_size >= BTB) {
        unsigned short* BTc = (unsigned short*)d_ws;
        cvt_w1<<<256, 256, 0, stream>>>(W1, BTc);
        fused_mlp<false><<<grid_main, 256, 0, stream>>>(z, nullptr, eli, E, nnodes, BTc, b1, W2, b2, out);
    } else {
        naive_edge<<<E, 128, 0, stream>>>(z, eli, E, nnodes, W1, b1, W2, b2, out);
    }
}